// Round 1
// baseline (3703.882 us; speedup 1.0000x reference)
//
#include <hip/hip_runtime.h>
#include <cfloat>
#include <math.h>

#define NEG_SLOPE 0.2f

// ---------------- CSR construction ----------------

__global__ void count_deg_k(const int* __restrict__ dst, int* __restrict__ deg, int E) {
    int i = blockIdx.x * 256 + threadIdx.x;
    if (i < E) atomicAdd(&deg[dst[i]], 1);
}

__global__ void scan_k(const int* __restrict__ deg, int* __restrict__ off, int n) {
    __shared__ int part[1024];
    int tid = threadIdx.x;
    int chunk = (n + 1023) >> 10;
    int beg = tid * chunk;
    int end = min(beg + chunk, n);
    int s = 0;
    for (int i = beg; i < end; ++i) s += deg[i];
    part[tid] = s;
    __syncthreads();
    for (int d = 1; d < 1024; d <<= 1) {
        int v = (tid >= d) ? part[tid - d] : 0;
        __syncthreads();
        part[tid] += v;
        __syncthreads();
    }
    int run = (tid > 0) ? part[tid - 1] : 0;
    for (int i = beg; i < end; ++i) { off[i] = run; run += deg[i]; }
    if (tid == 1023) off[n] = part[1023];
}

__global__ void scatter_k(const int* __restrict__ src, const int* __restrict__ dst,
                          const int* __restrict__ off, int* __restrict__ cur,
                          int* __restrict__ srcp, int* __restrict__ dstp, int E) {
    int i = blockIdx.x * 256 + threadIdx.x;
    if (i >= E) return;
    int d = dst[i];
    int p = off[d] + atomicAdd(&cur[d], 1);
    srcp[p] = src[i];
    dstp[p] = d;
}

// ---------------- small-B GEMM: C[n,j] = sum_k A[n,k]*B[k,j] ----------------

template<int K, int OUT>
__global__ __launch_bounds__(256) void gemm_k(const float* __restrict__ A,
                                              const float* __restrict__ B,
                                              float* __restrict__ C, int nrows) {
    constexpr int KT = (K * OUT > 8192) ? 64 : K;   // cap LDS tile at 32KB
    __shared__ float Bs[KT * OUT];
    constexpr int RPB = 256 / OUT;
    int ty = threadIdx.x / OUT, tx = threadIdx.x % OUT;
    int row = blockIdx.x * RPB + ty;
    const float* a = A + (size_t)row * K;
    float acc = 0.f;
    for (int k0 = 0; k0 < K; k0 += KT) {
        __syncthreads();
        for (int i = threadIdx.x; i < KT * OUT; i += 256) Bs[i] = B[(size_t)k0 * OUT + i];
        __syncthreads();
        if (row < nrows) {
#pragma unroll 8
            for (int k = 0; k < KT; ++k) acc = fmaf(a[k0 + k], Bs[k * OUT + tx], acc);
        }
    }
    if (row < nrows) C[(size_t)row * OUT + tx] = acc;
}

// ---------------- attention logits ----------------

template<int H, int D>
__global__ void elr_k(const float* __restrict__ feat, const float* __restrict__ al,
                      const float* __restrict__ ar, float* __restrict__ el,
                      float* __restrict__ er, int n) {
    int i = blockIdx.x * 256 + threadIdx.x;   // i = node*H + h
    if (i >= n * H) return;
    int h = i % H;
    const float* f = feat + (size_t)(i / H) * (H * D) + h * D;
    float sl = 0.f, sr = 0.f;
#pragma unroll
    for (int d = 0; d < D; ++d) {
        sl = fmaf(f[d], al[h * D + d], sl);
        sr = fmaf(f[d], ar[h * D + d], sr);
    }
    el[i] = sl; er[i] = sr;
}

template<int H>
__global__ void ep_k(const int* __restrict__ srcp, const int* __restrict__ dstp,
                     const float* __restrict__ el, const float* __restrict__ er,
                     float* __restrict__ ep, int E) {
    int i = blockIdx.x * 256 + threadIdx.x;   // CSR position
    if (i >= E) return;
    int s = srcp[i], d = dstp[i];
#pragma unroll
    for (int h = 0; h < H; ++h) {
        float x = el[s * H + h] + er[d * H + h];
        ep[(size_t)i * H + h] = x > 0.f ? x : NEG_SLOPE * x;
    }
}

// ---------------- per-node softmax + aggregation + residual + ELU + BN ----------------

template<int H, int D, bool ACT>
__global__ __launch_bounds__(64) void gat_node_k(
    const int* __restrict__ off, const int* __restrict__ srcp,
    const float* __restrict__ ep, const float* __restrict__ feat,
    const float* __restrict__ res, const float* __restrict__ bias,
    const float* __restrict__ bg, const float* __restrict__ bb,
    const float* __restrict__ bm, const float* __restrict__ bv,
    float* __restrict__ hout) {
    constexpr int HD = H * D;
    int n = blockIdx.x;
    int lane = threadIdx.x;
    int beg = off[n], end = off[n + 1];
    __shared__ float lm[H], ls[H];
    constexpr int CH = 64 / H;
    int h = lane % H;
    int c = lane / H;
    float mv = -FLT_MAX;
    for (int i0 = beg; i0 < end; i0 += CH) {
        int i = i0 + c;
        if (i < end) mv = fmaxf(mv, ep[(size_t)i * H + h]);
    }
#pragma unroll
    for (int m = H; m < 64; m <<= 1) mv = fmaxf(mv, __shfl_xor(mv, m, 64));
    float sv = 0.f;
    for (int i0 = beg; i0 < end; i0 += CH) {
        int i = i0 + c;
        if (i < end) sv += __expf(ep[(size_t)i * H + h] - mv);
    }
#pragma unroll
    for (int m = H; m < 64; m <<= 1) sv += __shfl_xor(sv, m, 64);
    if (lane < H) { lm[lane] = mv; ls[lane] = sv; }
    __syncthreads();

    int k0 = lane;
    int h0 = k0 / D; if (h0 > H - 1) h0 = H - 1;
    float m0 = lm[h0], inv0 = 1.f / ls[h0];
    float acc0 = 0.f;
#if 1
    float acc1 = 0.f, m1 = 0.f, inv1 = 0.f;
    int k1 = lane + 64, h1 = 0;
    if constexpr (HD > 64) { h1 = k1 / D; m1 = lm[h1]; inv1 = 1.f / ls[h1]; }
#endif
    for (int i = beg; i < end; ++i) {
        int s = srcp[i];
        const float* frow = feat + (size_t)s * HD;
        if (HD > 64 || lane < HD) {
            float w = __expf(ep[(size_t)i * H + h0] - m0) * inv0;
            acc0 = fmaf(w, frow[k0], acc0);
        }
        if constexpr (HD > 64) {
            float w = __expf(ep[(size_t)i * H + h1] - m1) * inv1;
            acc1 = fmaf(w, frow[k1], acc1);
        }
    }
#pragma unroll
    for (int r = 0; r < (HD + 63) / 64; ++r) {
        int k = lane + 64 * r;
        if (k < HD) {
            float x = (r == 0 ? acc0 : acc1) + res[(size_t)n * HD + k] + bias[k];
            if (ACT) x = x > 0.f ? x : expm1f(x);
            hout[(size_t)n * HD + k] = (x - bm[k]) * (bg[k] * rsqrtf(bv[k] + 1e-5f)) + bb[k];
        }
    }
}

// ---------------- fused edge classifier (8 edges per wave) ----------------
// z1 = relu(ef@Wc1[64:192] + u1[src] + u2[dst] + bc1), ef = relu(ed@We + be)
__global__ __launch_bounds__(256) void edge_cls_k(
    const float* __restrict__ u1, const float* __restrict__ u2,
    const float* __restrict__ edf,
    const int* __restrict__ src, const int* __restrict__ dst,
    const float* __restrict__ We, const float* __restrict__ be,
    const float* __restrict__ Wc1p, const float* __restrict__ bc1,
    const float* __restrict__ Wc2, const float* __restrict__ bc2,
    const float* __restrict__ Wc3, const float* __restrict__ bc3,
    float* __restrict__ out, int E) {
    __shared__ float edA[4][8][64];
    __shared__ float efA[4][8][128];
    __shared__ float z1A[4][8][32];
    __shared__ float z2A[4][8][16];
    int t = threadIdx.x, w = t >> 6, lane = t & 63;
    int e0 = blockIdx.x * 32 + w * 8;

    // stage edge-feature rows
#pragma unroll
    for (int ei = 0; ei < 8; ++ei) {
        int e = e0 + ei;
        edA[w][ei][lane] = (e < E) ? edf[(size_t)e * 64 + lane] : 0.f;
    }
    __syncthreads();

    // ef = relu(ed @ We + be), lane owns output cols lane and lane+64
    float acc[8][2];
    float be0 = be[lane], be1 = be[lane + 64];
#pragma unroll
    for (int ei = 0; ei < 8; ++ei) { acc[ei][0] = be0; acc[ei][1] = be1; }
    for (int k4 = 0; k4 < 16; ++k4) {
        float4 a4[8];
#pragma unroll
        for (int ei = 0; ei < 8; ++ei) a4[ei] = *(const float4*)&edA[w][ei][k4 * 4];
#pragma unroll
        for (int kk = 0; kk < 4; ++kk) {
            int k = k4 * 4 + kk;
            float w0 = We[k * 128 + lane];
            float w1 = We[k * 128 + lane + 64];
#pragma unroll
            for (int ei = 0; ei < 8; ++ei) {
                float a = ((const float*)&a4[ei])[kk];
                acc[ei][0] = fmaf(a, w0, acc[ei][0]);
                acc[ei][1] = fmaf(a, w1, acc[ei][1]);
            }
        }
    }
#pragma unroll
    for (int ei = 0; ei < 8; ++ei) {
        efA[w][ei][lane]      = fmaxf(acc[ei][0], 0.f);
        efA[w][ei][lane + 64] = fmaxf(acc[ei][1], 0.f);
    }
    __syncthreads();

    // z1: col = lane&31, half-wave owns 4 edges
    int col = lane & 31;
    int eh = (lane >> 5) * 4;
    float accz[4];
#pragma unroll
    for (int q = 0; q < 4; ++q) accz[q] = bc1[col];
    for (int k4 = 0; k4 < 32; ++k4) {
        float4 a4[4];
#pragma unroll
        for (int q = 0; q < 4; ++q) a4[q] = *(const float4*)&efA[w][eh + q][k4 * 4];
#pragma unroll
        for (int kk = 0; kk < 4; ++kk) {
            float b = Wc1p[(k4 * 4 + kk) * 32 + col];
#pragma unroll
            for (int q = 0; q < 4; ++q) accz[q] = fmaf(((const float*)&a4[q])[kk], b, accz[q]);
        }
    }
#pragma unroll
    for (int q = 0; q < 4; ++q) {
        int e = e0 + eh + q;
        int es = (e < E) ? src[e] : 0;
        int ed = (e < E) ? dst[e] : 0;
        float z = accz[q] + u1[(size_t)es * 32 + col] + u2[(size_t)ed * 32 + col];
        z1A[w][eh + q][col] = fmaxf(z, 0.f);
    }
    __syncthreads();

    // z2 = relu(z1 @ Wc2 + bc2): col = lane&15, eq = lane>>4 handles edges eq, eq+4
    {
        int c2 = lane & 15, eq = lane >> 4;
        float a0 = bc2[c2], a1 = bc2[c2];
#pragma unroll 4
        for (int k = 0; k < 32; ++k) {
            float b = Wc2[k * 16 + c2];
            a0 = fmaf(z1A[w][eq][k],     b, a0);
            a1 = fmaf(z1A[w][eq + 4][k], b, a1);
        }
        z2A[w][eq][c2]     = fmaxf(a0, 0.f);
        z2A[w][eq + 4][c2] = fmaxf(a1, 0.f);
    }
    __syncthreads();

    // out = z2 @ Wc3 + bc3
    if (lane < 16) {
        int ei = lane >> 1, cc = lane & 1;
        int e = e0 + ei;
        if (e < E) {
            float a = bc3[cc];
#pragma unroll
            for (int k = 0; k < 16; ++k) a = fmaf(z2A[w][ei][k], Wc3[k * 2 + cc], a);
            out[(size_t)e * 2 + cc] = a;
        }
    }
}

// ---------------- launch ----------------

extern "C" void kernel_launch(void* const* d_in, const int* in_sizes, int n_in,
                              void* d_out, int out_size, void* d_ws, size_t ws_size,
                              hipStream_t stream) {
    const float* node_feats = (const float*)d_in[0];
    const float* edge_feats = (const float*)d_in[1];
    const int*   src  = (const int*)d_in[2];
    const int*   dst  = (const int*)d_in[3];
    const float* W0   = (const float*)d_in[4];
    const float* al0  = (const float*)d_in[5];
    const float* ar0  = (const float*)d_in[6];
    const float* b0   = (const float*)d_in[7];
    const float* g0   = (const float*)d_in[8];
    const float* bt0  = (const float*)d_in[9];
    const float* m0   = (const float*)d_in[10];
    const float* v0   = (const float*)d_in[11];
    const float* W1   = (const float*)d_in[12];
    const float* al1  = (const float*)d_in[13];
    const float* ar1  = (const float*)d_in[14];
    const float* b1   = (const float*)d_in[15];
    const float* Wr1  = (const float*)d_in[16];
    const float* g1   = (const float*)d_in[17];
    const float* bt1  = (const float*)d_in[18];
    const float* m1   = (const float*)d_in[19];
    const float* v1   = (const float*)d_in[20];
    const float* W2   = (const float*)d_in[21];
    const float* al2  = (const float*)d_in[22];
    const float* ar2  = (const float*)d_in[23];
    const float* b2   = (const float*)d_in[24];
    const float* Wr2  = (const float*)d_in[25];
    const float* g2   = (const float*)d_in[26];
    const float* bt2  = (const float*)d_in[27];
    const float* v2m  = (const float*)d_in[28];   // m2
    const float* v2v  = (const float*)d_in[29];   // v2
    const float* We   = (const float*)d_in[30];
    const float* be   = (const float*)d_in[31];
    const float* Wc1  = (const float*)d_in[32];
    const float* bc1  = (const float*)d_in[33];
    const float* Wc2  = (const float*)d_in[34];
    const float* bc2  = (const float*)d_in[35];
    const float* Wc3  = (const float*)d_in[36];
    const float* bc3  = (const float*)d_in[37];
    float* out = (float*)d_out;

    const int N = in_sizes[0] / 128;
    const int E = in_sizes[2];

    char* p = (char*)d_ws;
    auto alloc = [&](size_t bytes) -> void* {
        void* r = (void*)p;
        p += (bytes + 255) & ~(size_t)255;
        return r;
    };
    int*   deg  = (int*)alloc((size_t)N * 4);
    int*   cur  = (int*)alloc((size_t)N * 4);
    int*   off  = (int*)alloc((size_t)(N + 1) * 4);
    int*   srcp = (int*)alloc((size_t)E * 4);
    int*   dstp = (int*)alloc((size_t)E * 4);
    float* ep   = (float*)alloc((size_t)E * 8 * 4);
    float* feat = (float*)alloc((size_t)N * 128 * 4);
    float* resf = (float*)alloc((size_t)N * 64 * 4);
    float* h1   = (float*)alloc((size_t)N * 128 * 4);
    float* h2   = (float*)alloc((size_t)N * 64 * 4);
    float* h3   = (float*)alloc((size_t)N * 32 * 4);
    float* el   = (float*)alloc((size_t)N * 8 * 4);
    float* er   = (float*)alloc((size_t)N * 8 * 4);
    float* u1   = h1;            // h1 dead by the time u1/u2 are built
    float* u2   = h1 + (size_t)N * 32;

    hipMemsetAsync(deg, 0, (size_t)N * 4, stream);
    hipMemsetAsync(cur, 0, (size_t)N * 4, stream);

    int eb = (E + 255) / 256;
    count_deg_k<<<eb, 256, 0, stream>>>(dst, deg, E);
    scan_k<<<1, 1024, 0, stream>>>(deg, off, N);
    scatter_k<<<eb, 256, 0, stream>>>(src, dst, off, cur, srcp, dstp, E);

    // ---- Layer 0: 128 -> 8x16, identity residual, ELU, BN ----
    gemm_k<128,128><<<(N + 1) / 2, 256, 0, stream>>>(node_feats, W0, feat, N);
    elr_k<8,16><<<(N * 8 + 255) / 256, 256, 0, stream>>>(feat, al0, ar0, el, er, N);
    ep_k<8><<<eb, 256, 0, stream>>>(srcp, dstp, el, er, ep, E);
    gat_node_k<8,16,true><<<N, 64, 0, stream>>>(off, srcp, ep, feat, node_feats,
                                                b0, g0, bt0, m0, v0, h1);
    // ---- Layer 1: 128 -> 8x8, projected residual, ELU, BN ----
    gemm_k<128,64><<<(N + 3) / 4, 256, 0, stream>>>(h1, W1, feat, N);
    gemm_k<128,64><<<(N + 3) / 4, 256, 0, stream>>>(h1, Wr1, resf, N);
    elr_k<8,8><<<(N * 8 + 255) / 256, 256, 0, stream>>>(feat, al1, ar1, el, er, N);
    ep_k<8><<<eb, 256, 0, stream>>>(srcp, dstp, el, er, ep, E);
    gat_node_k<8,8,true><<<N, 64, 0, stream>>>(off, srcp, ep, feat, resf,
                                               b1, g1, bt1, m1, v1, h2);
    // ---- Layer 2: 64 -> 1x32, projected residual, no act, BN ----
    gemm_k<64,32><<<(N + 7) / 8, 256, 0, stream>>>(h2, W2, feat, N);
    gemm_k<64,32><<<(N + 7) / 8, 256, 0, stream>>>(h2, Wr2, resf, N);
    elr_k<1,32><<<(N + 255) / 256, 256, 0, stream>>>(feat, al2, ar2, el, er, N);
    ep_k<1><<<eb, 256, 0, stream>>>(srcp, dstp, el, er, ep, E);
    gat_node_k<1,32,false><<<N, 64, 0, stream>>>(off, srcp, ep, feat, resf,
                                                 b2, g2, bt2, v2m, v2v, h3);
    // ---- per-node halves of z1 ----
    gemm_k<32,32><<<(N + 7) / 8, 256, 0, stream>>>(h3, Wc1,           u1, N);
    gemm_k<32,32><<<(N + 7) / 8, 256, 0, stream>>>(h3, Wc1 + 32 * 32, u2, N);
    // ---- fused edge classifier ----
    edge_cls_k<<<(E + 31) / 32, 256, 0, stream>>>(u1, u2, edge_feats, src, dst,
                                                  We, be, Wc1 + 64 * 32, bc1,
                                                  Wc2, bc2, Wc3, bc3, out, E);
}

// Round 2
// 1064.340 us; speedup vs baseline: 3.4800x; 3.4800x over previous
//
#include <hip/hip_runtime.h>
#include <cfloat>
#include <math.h>

#define NEG_SLOPE 0.2f

typedef short short8 __attribute__((ext_vector_type(8)));
typedef float f32x4 __attribute__((ext_vector_type(4)));

__device__ __forceinline__ short f2bf(float x) {
    unsigned u = __float_as_uint(x);
    u += 0x7fffu + ((u >> 16) & 1u);
    return (short)(u >> 16);
}

// ---------------- CSR construction ----------------

__global__ void count_deg_k(const int* __restrict__ dst, int* __restrict__ deg, int E) {
    int i = blockIdx.x * 256 + threadIdx.x;
    if (i < E) atomicAdd(&deg[dst[i]], 1);
}

__global__ void scan_k(const int* __restrict__ deg, int* __restrict__ off, int n) {
    __shared__ int part[1024];
    int tid = threadIdx.x;
    int chunk = (n + 1023) >> 10;
    int beg = tid * chunk;
    int end = min(beg + chunk, n);
    int s = 0;
    for (int i = beg; i < end; ++i) s += deg[i];
    part[tid] = s;
    __syncthreads();
    for (int d = 1; d < 1024; d <<= 1) {
        int v = (tid >= d) ? part[tid - d] : 0;
        __syncthreads();
        part[tid] += v;
        __syncthreads();
    }
    int run = (tid > 0) ? part[tid - 1] : 0;
    for (int i = beg; i < end; ++i) { off[i] = run; run += deg[i]; }
    if (tid == 1023) off[n] = part[1023];
}

__global__ void scatter_k(const int* __restrict__ src, const int* __restrict__ dst,
                          const int* __restrict__ off, int* __restrict__ cur,
                          int* __restrict__ srcp, int* __restrict__ dstp, int E) {
    int i = blockIdx.x * 256 + threadIdx.x;
    if (i >= E) return;
    int d = dst[i];
    int p = off[d] + atomicAdd(&cur[d], 1);
    srcp[p] = src[i];
    dstp[p] = d;
}

// ---------------- small-B GEMM: C[n,j] = sum_k A[n,k]*B[k,j] ----------------

template<int K, int OUT>
__global__ __launch_bounds__(256) void gemm_k(const float* __restrict__ A,
                                              const float* __restrict__ B,
                                              float* __restrict__ C, int nrows) {
    constexpr int KT = (K * OUT > 8192) ? 64 : K;   // cap LDS tile at 32KB
    __shared__ float Bs[KT * OUT];
    constexpr int RPB = 256 / OUT;
    int ty = threadIdx.x / OUT, tx = threadIdx.x % OUT;
    int row = blockIdx.x * RPB + ty;
    const float* a = A + (size_t)row * K;
    float acc = 0.f;
    for (int k0 = 0; k0 < K; k0 += KT) {
        __syncthreads();
        for (int i = threadIdx.x; i < KT * OUT; i += 256) Bs[i] = B[(size_t)k0 * OUT + i];
        __syncthreads();
        if (row < nrows) {
#pragma unroll 8
            for (int k = 0; k < KT; ++k) acc = fmaf(a[k0 + k], Bs[k * OUT + tx], acc);
        }
    }
    if (row < nrows) C[(size_t)row * OUT + tx] = acc;
}

// ---------------- attention logits ----------------

template<int H, int D>
__global__ void elr_k(const float* __restrict__ feat, const float* __restrict__ al,
                      const float* __restrict__ ar, float* __restrict__ el,
                      float* __restrict__ er, int n) {
    int i = blockIdx.x * 256 + threadIdx.x;   // i = node*H + h
    if (i >= n * H) return;
    int h = i % H;
    const float* f = feat + (size_t)(i / H) * (H * D) + h * D;
    float sl = 0.f, sr = 0.f;
#pragma unroll
    for (int d = 0; d < D; ++d) {
        sl = fmaf(f[d], al[h * D + d], sl);
        sr = fmaf(f[d], ar[h * D + d], sr);
    }
    el[i] = sl; er[i] = sr;
}

template<int H>
__global__ void ep_k(const int* __restrict__ srcp, const int* __restrict__ dstp,
                     const float* __restrict__ el, const float* __restrict__ er,
                     float* __restrict__ ep, int E) {
    int i = blockIdx.x * 256 + threadIdx.x;   // CSR position
    if (i >= E) return;
    int s = srcp[i], d = dstp[i];
#pragma unroll
    for (int h = 0; h < H; ++h) {
        float x = el[s * H + h] + er[d * H + h];
        ep[(size_t)i * H + h] = x > 0.f ? x : NEG_SLOPE * x;
    }
}

// ---------------- per-node softmax + aggregation + residual + ELU + BN ----------------

template<int H, int D, bool ACT>
__global__ __launch_bounds__(64) void gat_node_k(
    const int* __restrict__ off, const int* __restrict__ srcp,
    const float* __restrict__ ep, const float* __restrict__ feat,
    const float* __restrict__ res, const float* __restrict__ bias,
    const float* __restrict__ bg, const float* __restrict__ bb,
    const float* __restrict__ bm, const float* __restrict__ bv,
    float* __restrict__ hout) {
    constexpr int HD = H * D;
    int n = blockIdx.x;
    int lane = threadIdx.x;
    int beg = off[n], end = off[n + 1];
    __shared__ float lm[H], ls[H];
    constexpr int CH = 64 / H;
    int h = lane % H;
    int c = lane / H;
    float mv = -FLT_MAX;
    for (int i0 = beg; i0 < end; i0 += CH) {
        int i = i0 + c;
        if (i < end) mv = fmaxf(mv, ep[(size_t)i * H + h]);
    }
#pragma unroll
    for (int m = H; m < 64; m <<= 1) mv = fmaxf(mv, __shfl_xor(mv, m, 64));
    float sv = 0.f;
    for (int i0 = beg; i0 < end; i0 += CH) {
        int i = i0 + c;
        if (i < end) sv += __expf(ep[(size_t)i * H + h] - mv);
    }
#pragma unroll
    for (int m = H; m < 64; m <<= 1) sv += __shfl_xor(sv, m, 64);
    if (lane < H) { lm[lane] = mv; ls[lane] = sv; }
    __syncthreads();

    int k0 = lane;
    int h0 = k0 / D; if (h0 > H - 1) h0 = H - 1;
    float m0 = lm[h0], inv0 = 1.f / ls[h0];
    float acc0 = 0.f;
    float acc1 = 0.f, m1 = 0.f, inv1 = 0.f;
    int k1 = lane + 64, h1 = 0;
    if constexpr (HD > 64) { h1 = k1 / D; m1 = lm[h1]; inv1 = 1.f / ls[h1]; }
    for (int i = beg; i < end; ++i) {
        int s = srcp[i];
        const float* frow = feat + (size_t)s * HD;
        if (HD > 64 || lane < HD) {
            float w = __expf(ep[(size_t)i * H + h0] - m0) * inv0;
            acc0 = fmaf(w, frow[k0], acc0);
        }
        if constexpr (HD > 64) {
            float w = __expf(ep[(size_t)i * H + h1] - m1) * inv1;
            acc1 = fmaf(w, frow[k1], acc1);
        }
    }
#pragma unroll
    for (int r = 0; r < (HD + 63) / 64; ++r) {
        int k = lane + 64 * r;
        if (k < HD) {
            float x = (r == 0 ? acc0 : acc1) + res[(size_t)n * HD + k] + bias[k];
            if (ACT) x = x > 0.f ? x : expm1f(x);
            hout[(size_t)n * HD + k] = (x - bm[k]) * (bg[k] * rsqrtf(bv[k] + 1e-5f)) + bb[k];
        }
    }
}

// ---------------- fused edge classifier: MFMA pipeline, 16 edges/wave ----------------
// ef = relu(ed@We+be)  [16x64 @ 64x128, 2 k-tiles x 8 n-tiles MFMA]
// z1 = relu(ef@Wc1p + u1[src] + u2[dst] + bc1)  [16x128 @ 128x32]
// z2 = relu(z1@Wc2+bc2), out = z2@Wc3+bc3 (VALU)
__global__ __launch_bounds__(256) void edge_cls_k(
    const float* __restrict__ u1, const float* __restrict__ u2,
    const float* __restrict__ edf,
    const int* __restrict__ src, const int* __restrict__ dst,
    const float* __restrict__ We, const float* __restrict__ be,
    const float* __restrict__ Wc1p, const float* __restrict__ bc1,
    const float* __restrict__ Wc2, const float* __restrict__ bc2,
    const float* __restrict__ Wc3, const float* __restrict__ bc3,
    float* __restrict__ out, int E) {
    // LDS: bf16 weights transposed [n][k] so B-frags are contiguous b128 reads.
    __shared__ short WeT[128 * 72];     // WeT[n*72+k], n<128, k<64   (18.4 KB)
    __shared__ short Wc1T[32 * 136];    // Wc1T[n*136+k], n<32, k<128 (8.7 KB)
    __shared__ short efA[4][16 * 136];  // per-wave ef bf16 [m][k]    (17.4 KB)
    __shared__ float z1A[4][16 * 36];   // per-wave z1 fp32           (9.2 KB)
    __shared__ float z2A[4][16 * 20];   // per-wave z2 fp32           (5.1 KB)

    int t = threadIdx.x;
    // ---- stage weights (once per block) ----
    for (int idx = t; idx < 64 * 128; idx += 256) {
        int k = idx >> 7, n = idx & 127;
        WeT[n * 72 + k] = f2bf(We[idx]);
    }
    for (int idx = t; idx < 128 * 32; idx += 256) {
        int k = idx >> 5, n = idx & 31;
        Wc1T[n * 136 + k] = f2bf(Wc1p[idx]);
    }
    __syncthreads();

    int w = t >> 6, lane = t & 63;
    int m = lane & 15, q = lane >> 4;
    int e0w = blockIdx.x * 64 + w * 16;
    short* efW = efA[w];
    float* z1W = z1A[w];
    float* z2W = z2A[w];

    // ---- phase 1: A-frags of edge-feature rows (A[m=lane&15][k=q*8+j]) ----
    int em = e0w + m;
    const float* rp = edf + (size_t)(em < E ? em : 0) * 64;
    float4 r0 = *(const float4*)(rp + q * 8);
    float4 r1 = *(const float4*)(rp + q * 8 + 4);
    float4 r2 = *(const float4*)(rp + 32 + q * 8);
    float4 r3 = *(const float4*)(rp + 32 + q * 8 + 4);
    short8 A0, A1;
    A0[0] = f2bf(r0.x); A0[1] = f2bf(r0.y); A0[2] = f2bf(r0.z); A0[3] = f2bf(r0.w);
    A0[4] = f2bf(r1.x); A0[5] = f2bf(r1.y); A0[6] = f2bf(r1.z); A0[7] = f2bf(r1.w);
    A1[0] = f2bf(r2.x); A1[1] = f2bf(r2.y); A1[2] = f2bf(r2.z); A1[3] = f2bf(r2.w);
    A1[4] = f2bf(r3.x); A1[5] = f2bf(r3.y); A1[6] = f2bf(r3.z); A1[7] = f2bf(r3.w);

    // ---- phase 2: ef = relu(ed@We+be), C layout col=lane&15, row=q*4+r ----
#pragma unroll
    for (int nt = 0; nt < 8; ++nt) {
        int col = nt * 16 + m;
        float bias = be[col];
        f32x4 acc = {bias, bias, bias, bias};
        short8 b0 = *(const short8*)&WeT[col * 72 + q * 8];
        short8 b1 = *(const short8*)&WeT[col * 72 + 32 + q * 8];
        acc = __builtin_amdgcn_mfma_f32_16x16x32_bf16(A0, b0, acc, 0, 0, 0);
        acc = __builtin_amdgcn_mfma_f32_16x16x32_bf16(A1, b1, acc, 0, 0, 0);
#pragma unroll
        for (int r = 0; r < 4; ++r)
            efW[(q * 4 + r) * 136 + col] = f2bf(fmaxf(acc[r], 0.f));
    }
    __syncthreads();

    // ---- phase 3: z1 = relu(ef@Wc1p + u1[src]+u2[dst]+bc1) ----
    short8 Az[4];
#pragma unroll
    for (int kt = 0; kt < 4; ++kt)
        Az[kt] = *(const short8*)&efW[m * 136 + kt * 32 + q * 8];
#pragma unroll
    for (int nt = 0; nt < 2; ++nt) {
        int col = nt * 16 + m;
        float bias = bc1[col];
        f32x4 acc = {bias, bias, bias, bias};
#pragma unroll
        for (int kt = 0; kt < 4; ++kt) {
            short8 b = *(const short8*)&Wc1T[col * 136 + kt * 32 + q * 8];
            acc = __builtin_amdgcn_mfma_f32_16x16x32_bf16(Az[kt], b, acc, 0, 0, 0);
        }
#pragma unroll
        for (int r = 0; r < 4; ++r) {
            int e = e0w + q * 4 + r;
            int ec = e < E ? e : 0;
            int s = src[ec], d = dst[ec];
            float z = acc[r] + u1[(size_t)s * 32 + col] + u2[(size_t)d * 32 + col];
            z1W[(q * 4 + r) * 36 + col] = fmaxf(z, 0.f);
        }
    }
    __syncthreads();

    // ---- phase 4: z2 = relu(z1@Wc2+bc2); lane: edge=lane&15, cols c4*4..+3 ----
    {
        int e = lane & 15, c4 = lane >> 4;
        float4 bv = *(const float4*)(bc2 + c4 * 4);
        float a0 = bv.x, a1 = bv.y, a2 = bv.z, a3 = bv.w;
#pragma unroll
        for (int k4 = 0; k4 < 8; ++k4) {
            float4 zz = *(const float4*)&z1W[e * 36 + k4 * 4];
            float zs[4] = {zz.x, zz.y, zz.z, zz.w};
#pragma unroll
            for (int j = 0; j < 4; ++j) {
                float4 wr = *(const float4*)(Wc2 + (k4 * 4 + j) * 16 + c4 * 4);
                a0 = fmaf(zs[j], wr.x, a0);
                a1 = fmaf(zs[j], wr.y, a1);
                a2 = fmaf(zs[j], wr.z, a2);
                a3 = fmaf(zs[j], wr.w, a3);
            }
        }
        float4 zo = {fmaxf(a0, 0.f), fmaxf(a1, 0.f), fmaxf(a2, 0.f), fmaxf(a3, 0.f)};
        *(float4*)&z2W[e * 20 + c4 * 4] = zo;
    }
    __syncthreads();

    // ---- phase 5: out = z2@Wc3+bc3 ----
    if (lane < 32) {
        int e = lane >> 1, c = lane & 1;
        int eg = e0w + e;
        if (eg < E) {
            float a = bc3[c];
#pragma unroll
            for (int k = 0; k < 16; ++k) a = fmaf(z2W[e * 20 + k], Wc3[k * 2 + c], a);
            out[(size_t)eg * 2 + c] = a;
        }
    }
}

// ---------------- launch ----------------

extern "C" void kernel_launch(void* const* d_in, const int* in_sizes, int n_in,
                              void* d_out, int out_size, void* d_ws, size_t ws_size,
                              hipStream_t stream) {
    const float* node_feats = (const float*)d_in[0];
    const float* edge_feats = (const float*)d_in[1];
    const int*   src  = (const int*)d_in[2];
    const int*   dst  = (const int*)d_in[3];
    const float* W0   = (const float*)d_in[4];
    const float* al0  = (const float*)d_in[5];
    const float* ar0  = (const float*)d_in[6];
    const float* b0   = (const float*)d_in[7];
    const float* g0   = (const float*)d_in[8];
    const float* bt0  = (const float*)d_in[9];
    const float* m0   = (const float*)d_in[10];
    const float* v0   = (const float*)d_in[11];
    const float* W1   = (const float*)d_in[12];
    const float* al1  = (const float*)d_in[13];
    const float* ar1  = (const float*)d_in[14];
    const float* b1   = (const float*)d_in[15];
    const float* Wr1  = (const float*)d_in[16];
    const float* g1   = (const float*)d_in[17];
    const float* bt1  = (const float*)d_in[18];
    const float* m1   = (const float*)d_in[19];
    const float* v1   = (const float*)d_in[20];
    const float* W2   = (const float*)d_in[21];
    const float* al2  = (const float*)d_in[22];
    const float* ar2  = (const float*)d_in[23];
    const float* b2   = (const float*)d_in[24];
    const float* Wr2  = (const float*)d_in[25];
    const float* g2   = (const float*)d_in[26];
    const float* bt2  = (const float*)d_in[27];
    const float* v2m  = (const float*)d_in[28];   // m2
    const float* v2v  = (const float*)d_in[29];   // v2
    const float* We   = (const float*)d_in[30];
    const float* be   = (const float*)d_in[31];
    const float* Wc1  = (const float*)d_in[32];
    const float* bc1  = (const float*)d_in[33];
    const float* Wc2  = (const float*)d_in[34];
    const float* bc2  = (const float*)d_in[35];
    const float* Wc3  = (const float*)d_in[36];
    const float* bc3  = (const float*)d_in[37];
    float* out = (float*)d_out;

    const int N = in_sizes[0] / 128;
    const int E = in_sizes[2];

    char* p = (char*)d_ws;
    auto alloc = [&](size_t bytes) -> void* {
        void* r = (void*)p;
        p += (bytes + 255) & ~(size_t)255;
        return r;
    };
    int*   deg  = (int*)alloc((size_t)N * 4);
    int*   cur  = (int*)alloc((size_t)N * 4);
    int*   off  = (int*)alloc((size_t)(N + 1) * 4);
    int*   srcp = (int*)alloc((size_t)E * 4);
    int*   dstp = (int*)alloc((size_t)E * 4);
    float* ep   = (float*)alloc((size_t)E * 8 * 4);
    float* feat = (float*)alloc((size_t)N * 128 * 4);
    float* resf = (float*)alloc((size_t)N * 64 * 4);
    float* h1   = (float*)alloc((size_t)N * 128 * 4);
    float* h2   = (float*)alloc((size_t)N * 64 * 4);
    float* h3   = (float*)alloc((size_t)N * 32 * 4);
    float* el   = (float*)alloc((size_t)N * 8 * 4);
    float* er   = (float*)alloc((size_t)N * 8 * 4);
    float* u1   = h1;            // h1 dead by the time u1/u2 are built
    float* u2   = h1 + (size_t)N * 32;

    hipMemsetAsync(deg, 0, (size_t)N * 4, stream);
    hipMemsetAsync(cur, 0, (size_t)N * 4, stream);

    int eb = (E + 255) / 256;
    count_deg_k<<<eb, 256, 0, stream>>>(dst, deg, E);
    scan_k<<<1, 1024, 0, stream>>>(deg, off, N);
    scatter_k<<<eb, 256, 0, stream>>>(src, dst, off, cur, srcp, dstp, E);

    // ---- Layer 0: 128 -> 8x16, identity residual, ELU, BN ----
    gemm_k<128,128><<<(N + 1) / 2, 256, 0, stream>>>(node_feats, W0, feat, N);
    elr_k<8,16><<<(N * 8 + 255) / 256, 256, 0, stream>>>(feat, al0, ar0, el, er, N);
    ep_k<8><<<eb, 256, 0, stream>>>(srcp, dstp, el, er, ep, E);
    gat_node_k<8,16,true><<<N, 64, 0, stream>>>(off, srcp, ep, feat, node_feats,
                                                b0, g0, bt0, m0, v0, h1);
    // ---- Layer 1: 128 -> 8x8, projected residual, ELU, BN ----
    gemm_k<128,64><<<(N + 3) / 4, 256, 0, stream>>>(h1, W1, feat, N);
    gemm_k<128,64><<<(N + 3) / 4, 256, 0, stream>>>(h1, Wr1, resf, N);
    elr_k<8,8><<<(N * 8 + 255) / 256, 256, 0, stream>>>(feat, al1, ar1, el, er, N);
    ep_k<8><<<eb, 256, 0, stream>>>(srcp, dstp, el, er, ep, E);
    gat_node_k<8,8,true><<<N, 64, 0, stream>>>(off, srcp, ep, feat, resf,
                                               b1, g1, bt1, m1, v1, h2);
    // ---- Layer 2: 64 -> 1x32, projected residual, no act, BN ----
    gemm_k<64,32><<<(N + 7) / 8, 256, 0, stream>>>(h2, W2, feat, N);
    gemm_k<64,32><<<(N + 7) / 8, 256, 0, stream>>>(h2, Wr2, resf, N);
    elr_k<1,32><<<(N + 255) / 256, 256, 0, stream>>>(feat, al2, ar2, el, er, N);
    ep_k<1><<<eb, 256, 0, stream>>>(srcp, dstp, el, er, ep, E);
    gat_node_k<1,32,false><<<N, 64, 0, stream>>>(off, srcp, ep, feat, resf,
                                                 b2, g2, bt2, v2m, v2v, h3);
    // ---- per-node halves of z1 ----
    gemm_k<32,32><<<(N + 7) / 8, 256, 0, stream>>>(h3, Wc1,           u1, N);
    gemm_k<32,32><<<(N + 7) / 8, 256, 0, stream>>>(h3, Wc1 + 32 * 32, u2, N);
    // ---- fused edge classifier (MFMA) ----
    edge_cls_k<<<(E + 63) / 64, 256, 0, stream>>>(u1, u2, edge_feats, src, dst,
                                                  We, be, Wc1 + 64 * 32, bc1,
                                                  Wc2, bc2, Wc3, bc3, out, E);
}

// Round 3
// 752.212 us; speedup vs baseline: 4.9240x; 1.4149x over previous
//
#include <hip/hip_runtime.h>
#include <cfloat>
#include <math.h>

#define NEG_SLOPE 0.2f

typedef short short8 __attribute__((ext_vector_type(8)));
typedef float f32x4 __attribute__((ext_vector_type(4)));

__device__ __forceinline__ short f2bf(float x) {
    unsigned u = __float_as_uint(x);
    u += 0x7fffu + ((u >> 16) & 1u);
    return (short)(u >> 16);
}

// ---------------- CSR construction ----------------

__global__ void count_deg_k(const int* __restrict__ dst, int* __restrict__ deg, int E) {
    int i = blockIdx.x * 256 + threadIdx.x;
    if (i < E) atomicAdd(&deg[dst[i]], 1);
}

__global__ void scan_k(const int* __restrict__ deg, int* __restrict__ off, int n) {
    __shared__ int part[1024];
    int tid = threadIdx.x;
    int chunk = (n + 1023) >> 10;
    int beg = tid * chunk;
    int end = min(beg + chunk, n);
    int s = 0;
    for (int i = beg; i < end; ++i) s += deg[i];
    part[tid] = s;
    __syncthreads();
    for (int d = 1; d < 1024; d <<= 1) {
        int v = (tid >= d) ? part[tid - d] : 0;
        __syncthreads();
        part[tid] += v;
        __syncthreads();
    }
    int run = (tid > 0) ? part[tid - 1] : 0;
    for (int i = beg; i < end; ++i) { off[i] = run; run += deg[i]; }
    if (tid == 1023) off[n] = part[1023];
}

__global__ void scatter_k(const int* __restrict__ src, const int* __restrict__ dst,
                          const int* __restrict__ off, int* __restrict__ cur,
                          int* __restrict__ srcp, int* __restrict__ dstp, int E) {
    int i = blockIdx.x * 256 + threadIdx.x;
    if (i >= E) return;
    int d = dst[i];
    int p = off[d] + atomicAdd(&cur[d], 1);
    srcp[p] = src[i];
    dstp[p] = d;
}

// ---------------- register-blocked GEMM: C[n,j] = sum_k A[n,k]*B[k,j] ----------------
// 4 rows x CPT cols per thread; A+B tiles in LDS; blockIdx.y selects (B1,C1)/(B2,C2)
// so paired GEMMs sharing A fuse into one dispatch.

template<int K, int OUT>
__global__ __launch_bounds__(256) void gemm2_k(const float* __restrict__ A,
                                               const float* __restrict__ B1, float* __restrict__ C1,
                                               const float* __restrict__ B2, float* __restrict__ C2,
                                               int nrows) {
    constexpr int CPT  = (OUT >= 64) ? 8 : 4;   // cols per thread
    constexpr int CG   = OUT / CPT;             // threads per row-group
    constexpr int TY   = 256 / CG;              // row-groups per block
    constexpr int ROWS = TY * 4;                // rows per block
    constexpr int KT   = (K < 32) ? K : 32;     // K tile
    constexpr int KTP  = KT + 4;                // A stride pad (breaks bank aliasing)

    __shared__ float As[ROWS * KTP];
    __shared__ float Bs[KT * OUT];

    const float* B = blockIdx.y ? B2 : B1;
    float*       C = blockIdx.y ? C2 : C1;

    int t = threadIdx.x;
    int tx = t % CG, ty = t / CG;
    int row0 = blockIdx.x * ROWS;

    float acc[4][CPT];
#pragma unroll
    for (int r = 0; r < 4; ++r)
#pragma unroll
        for (int c = 0; c < CPT; ++c) acc[r][c] = 0.f;

    for (int k0 = 0; k0 < K; k0 += KT) {
        __syncthreads();
        // stage A tile (float4, zero-pad OOB rows)
#pragma unroll
        for (int i = t; i < ROWS * (KT / 4); i += 256) {
            int row = i / (KT / 4), c4 = i % (KT / 4);
            float4 v = {0.f, 0.f, 0.f, 0.f};
            if (row0 + row < nrows)
                v = *(const float4*)&A[(size_t)(row0 + row) * K + k0 + c4 * 4];
            *(float4*)&As[row * KTP + c4 * 4] = v;
        }
        // stage B tile
#pragma unroll
        for (int i = t; i < KT * (OUT / 4); i += 256) {
            int k = i / (OUT / 4), c4 = i % (OUT / 4);
            *(float4*)&Bs[k * OUT + c4 * 4] = *(const float4*)&B[(size_t)(k0 + k) * OUT + c4 * 4];
        }
        __syncthreads();

#pragma unroll
        for (int kk4 = 0; kk4 < KT / 4; ++kk4) {
            float4 a4[4];
#pragma unroll
            for (int r = 0; r < 4; ++r)
                a4[r] = *(const float4*)&As[(ty * 4 + r) * KTP + kk4 * 4];
#pragma unroll
            for (int j = 0; j < 4; ++j) {
                int kk = kk4 * 4 + j;
                float4 b4[CPT / 4];
#pragma unroll
                for (int c = 0; c < CPT / 4; ++c)
                    b4[c] = *(const float4*)&Bs[kk * OUT + tx * CPT + c * 4];
#pragma unroll
                for (int r = 0; r < 4; ++r) {
                    float a = ((const float*)&a4[r])[j];
#pragma unroll
                    for (int c = 0; c < CPT / 4; ++c) {
                        acc[r][c * 4 + 0] = fmaf(a, b4[c].x, acc[r][c * 4 + 0]);
                        acc[r][c * 4 + 1] = fmaf(a, b4[c].y, acc[r][c * 4 + 1]);
                        acc[r][c * 4 + 2] = fmaf(a, b4[c].z, acc[r][c * 4 + 2]);
                        acc[r][c * 4 + 3] = fmaf(a, b4[c].w, acc[r][c * 4 + 3]);
                    }
                }
            }
        }
    }

#pragma unroll
    for (int r = 0; r < 4; ++r) {
        int row = row0 + ty * 4 + r;
        if (row < nrows) {
#pragma unroll
            for (int c = 0; c < CPT / 4; ++c) {
                float4 v = {acc[r][c * 4 + 0], acc[r][c * 4 + 1], acc[r][c * 4 + 2], acc[r][c * 4 + 3]};
                *(float4*)&C[(size_t)row * OUT + tx * CPT + c * 4] = v;
            }
        }
    }
}

// ---------------- attention logits ----------------

template<int H, int D>
__global__ void elr_k(const float* __restrict__ feat, const float* __restrict__ al,
                      const float* __restrict__ ar, float* __restrict__ el,
                      float* __restrict__ er, int n) {
    int i = blockIdx.x * 256 + threadIdx.x;   // i = node*H + h
    if (i >= n * H) return;
    int h = i % H;
    const float* f = feat + (size_t)(i / H) * (H * D) + h * D;
    float sl = 0.f, sr = 0.f;
#pragma unroll
    for (int d = 0; d < D; ++d) {
        sl = fmaf(f[d], al[h * D + d], sl);
        sr = fmaf(f[d], ar[h * D + d], sr);
    }
    el[i] = sl; er[i] = sr;
}

template<int H>
__global__ void ep_k(const int* __restrict__ srcp, const int* __restrict__ dstp,
                     const float* __restrict__ el, const float* __restrict__ er,
                     float* __restrict__ ep, int E) {
    int i = blockIdx.x * 256 + threadIdx.x;   // CSR position
    if (i >= E) return;
    int s = srcp[i], d = dstp[i];
#pragma unroll
    for (int h = 0; h < H; ++h) {
        float x = el[s * H + h] + er[d * H + h];
        ep[(size_t)i * H + h] = x > 0.f ? x : NEG_SLOPE * x;
    }
}

// ---------------- per-node softmax + aggregation + residual + ELU + BN ----------------

template<int H, int D, bool ACT>
__global__ __launch_bounds__(64) void gat_node_k(
    const int* __restrict__ off, const int* __restrict__ srcp,
    const float* __restrict__ ep, const float* __restrict__ feat,
    const float* __restrict__ res, const float* __restrict__ bias,
    const float* __restrict__ bg, const float* __restrict__ bb,
    const float* __restrict__ bm, const float* __restrict__ bv,
    float* __restrict__ hout) {
    constexpr int HD = H * D;
    int n = blockIdx.x;
    int lane = threadIdx.x;
    int beg = off[n], end = off[n + 1];
    __shared__ float lm[H], ls[H];
    constexpr int CH = 64 / H;
    int h = lane % H;
    int c = lane / H;
    float mv = -FLT_MAX;
    for (int i0 = beg; i0 < end; i0 += CH) {
        int i = i0 + c;
        if (i < end) mv = fmaxf(mv, ep[(size_t)i * H + h]);
    }
#pragma unroll
    for (int m = H; m < 64; m <<= 1) mv = fmaxf(mv, __shfl_xor(mv, m, 64));
    float sv = 0.f;
    for (int i0 = beg; i0 < end; i0 += CH) {
        int i = i0 + c;
        if (i < end) sv += __expf(ep[(size_t)i * H + h] - mv);
    }
#pragma unroll
    for (int m = H; m < 64; m <<= 1) sv += __shfl_xor(sv, m, 64);
    if (lane < H) { lm[lane] = mv; ls[lane] = sv; }
    __syncthreads();

    int k0 = lane;
    int h0 = k0 / D; if (h0 > H - 1) h0 = H - 1;
    float m0 = lm[h0], inv0 = 1.f / ls[h0];
    float acc0 = 0.f;
    float acc1 = 0.f, m1 = 0.f, inv1 = 0.f;
    int k1 = lane + 64, h1 = 0;
    if constexpr (HD > 64) { h1 = k1 / D; m1 = lm[h1]; inv1 = 1.f / ls[h1]; }
    for (int i = beg; i < end; ++i) {
        int s = srcp[i];
        const float* frow = feat + (size_t)s * HD;
        if (HD > 64 || lane < HD) {
            float w = __expf(ep[(size_t)i * H + h0] - m0) * inv0;
            acc0 = fmaf(w, frow[k0], acc0);
        }
        if constexpr (HD > 64) {
            float w = __expf(ep[(size_t)i * H + h1] - m1) * inv1;
            acc1 = fmaf(w, frow[k1], acc1);
        }
    }
#pragma unroll
    for (int r = 0; r < (HD + 63) / 64; ++r) {
        int k = lane + 64 * r;
        if (k < HD) {
            float x = (r == 0 ? acc0 : acc1) + res[(size_t)n * HD + k] + bias[k];
            if (ACT) x = x > 0.f ? x : expm1f(x);
            hout[(size_t)n * HD + k] = (x - bm[k]) * (bg[k] * rsqrtf(bv[k] + 1e-5f)) + bb[k];
        }
    }
}

// ---------------- fused edge classifier: MFMA pipeline, 16 edges/wave ----------------

__global__ __launch_bounds__(256) void edge_cls_k(
    const float* __restrict__ u1, const float* __restrict__ u2,
    const float* __restrict__ edf,
    const int* __restrict__ src, const int* __restrict__ dst,
    const float* __restrict__ We, const float* __restrict__ be,
    const float* __restrict__ Wc1p, const float* __restrict__ bc1,
    const float* __restrict__ Wc2, const float* __restrict__ bc2,
    const float* __restrict__ Wc3, const float* __restrict__ bc3,
    float* __restrict__ out, int E) {
    __shared__ short WeT[128 * 72];
    __shared__ short Wc1T[32 * 136];
    __shared__ short efA[4][16 * 136];
    __shared__ float z1A[4][16 * 36];
    __shared__ float z2A[4][16 * 20];

    int t = threadIdx.x;
    for (int idx = t; idx < 64 * 128; idx += 256) {
        int k = idx >> 7, n = idx & 127;
        WeT[n * 72 + k] = f2bf(We[idx]);
    }
    for (int idx = t; idx < 128 * 32; idx += 256) {
        int k = idx >> 5, n = idx & 31;
        Wc1T[n * 136 + k] = f2bf(Wc1p[idx]);
    }
    __syncthreads();

    int w = t >> 6, lane = t & 63;
    int m = lane & 15, q = lane >> 4;
    int e0w = blockIdx.x * 64 + w * 16;
    short* efW = efA[w];
    float* z1W = z1A[w];
    float* z2W = z2A[w];

    int em = e0w + m;
    const float* rp = edf + (size_t)(em < E ? em : 0) * 64;
    float4 r0 = *(const float4*)(rp + q * 8);
    float4 r1 = *(const float4*)(rp + q * 8 + 4);
    float4 r2 = *(const float4*)(rp + 32 + q * 8);
    float4 r3 = *(const float4*)(rp + 32 + q * 8 + 4);
    short8 A0, A1;
    A0[0] = f2bf(r0.x); A0[1] = f2bf(r0.y); A0[2] = f2bf(r0.z); A0[3] = f2bf(r0.w);
    A0[4] = f2bf(r1.x); A0[5] = f2bf(r1.y); A0[6] = f2bf(r1.z); A0[7] = f2bf(r1.w);
    A1[0] = f2bf(r2.x); A1[1] = f2bf(r2.y); A1[2] = f2bf(r2.z); A1[3] = f2bf(r2.w);
    A1[4] = f2bf(r3.x); A1[5] = f2bf(r3.y); A1[6] = f2bf(r3.z); A1[7] = f2bf(r3.w);

#pragma unroll
    for (int nt = 0; nt < 8; ++nt) {
        int col = nt * 16 + m;
        float bias = be[col];
        f32x4 acc = {bias, bias, bias, bias};
        short8 b0 = *(const short8*)&WeT[col * 72 + q * 8];
        short8 b1 = *(const short8*)&WeT[col * 72 + 32 + q * 8];
        acc = __builtin_amdgcn_mfma_f32_16x16x32_bf16(A0, b0, acc, 0, 0, 0);
        acc = __builtin_amdgcn_mfma_f32_16x16x32_bf16(A1, b1, acc, 0, 0, 0);
#pragma unroll
        for (int r = 0; r < 4; ++r)
            efW[(q * 4 + r) * 136 + col] = f2bf(fmaxf(acc[r], 0.f));
    }
    __syncthreads();

    short8 Az[4];
#pragma unroll
    for (int kt = 0; kt < 4; ++kt)
        Az[kt] = *(const short8*)&efW[m * 136 + kt * 32 + q * 8];
#pragma unroll
    for (int nt = 0; nt < 2; ++nt) {
        int col = nt * 16 + m;
        float bias = bc1[col];
        f32x4 acc = {bias, bias, bias, bias};
#pragma unroll
        for (int kt = 0; kt < 4; ++kt) {
            short8 b = *(const short8*)&Wc1T[col * 136 + kt * 32 + q * 8];
            acc = __builtin_amdgcn_mfma_f32_16x16x32_bf16(Az[kt], b, acc, 0, 0, 0);
        }
#pragma unroll
        for (int r = 0; r < 4; ++r) {
            int e = e0w + q * 4 + r;
            int ec = e < E ? e : 0;
            int s = src[ec], d = dst[ec];
            float z = acc[r] + u1[(size_t)s * 32 + col] + u2[(size_t)d * 32 + col];
            z1W[(q * 4 + r) * 36 + col] = fmaxf(z, 0.f);
        }
    }
    __syncthreads();

    {
        int e = lane & 15, c4 = lane >> 4;
        float4 bv = *(const float4*)(bc2 + c4 * 4);
        float a0 = bv.x, a1 = bv.y, a2 = bv.z, a3 = bv.w;
#pragma unroll
        for (int k4 = 0; k4 < 8; ++k4) {
            float4 zz = *(const float4*)&z1W[e * 36 + k4 * 4];
            float zs[4] = {zz.x, zz.y, zz.z, zz.w};
#pragma unroll
            for (int j = 0; j < 4; ++j) {
                float4 wr = *(const float4*)(Wc2 + (k4 * 4 + j) * 16 + c4 * 4);
                a0 = fmaf(zs[j], wr.x, a0);
                a1 = fmaf(zs[j], wr.y, a1);
                a2 = fmaf(zs[j], wr.z, a2);
                a3 = fmaf(zs[j], wr.w, a3);
            }
        }
        float4 zo = {fmaxf(a0, 0.f), fmaxf(a1, 0.f), fmaxf(a2, 0.f), fmaxf(a3, 0.f)};
        *(float4*)&z2W[e * 20 + c4 * 4] = zo;
    }
    __syncthreads();

    if (lane < 32) {
        int e = lane >> 1, c = lane & 1;
        int eg = e0w + e;
        if (eg < E) {
            float a = bc3[c];
#pragma unroll
            for (int k = 0; k < 16; ++k) a = fmaf(z2W[e * 20 + k], Wc3[k * 2 + c], a);
            out[(size_t)eg * 2 + c] = a;
        }
    }
}

// ---------------- launch ----------------

extern "C" void kernel_launch(void* const* d_in, const int* in_sizes, int n_in,
                              void* d_out, int out_size, void* d_ws, size_t ws_size,
                              hipStream_t stream) {
    const float* node_feats = (const float*)d_in[0];
    const float* edge_feats = (const float*)d_in[1];
    const int*   src  = (const int*)d_in[2];
    const int*   dst  = (const int*)d_in[3];
    const float* W0   = (const float*)d_in[4];
    const float* al0  = (const float*)d_in[5];
    const float* ar0  = (const float*)d_in[6];
    const float* b0   = (const float*)d_in[7];
    const float* g0   = (const float*)d_in[8];
    const float* bt0  = (const float*)d_in[9];
    const float* m0   = (const float*)d_in[10];
    const float* v0   = (const float*)d_in[11];
    const float* W1   = (const float*)d_in[12];
    const float* al1  = (const float*)d_in[13];
    const float* ar1  = (const float*)d_in[14];
    const float* b1   = (const float*)d_in[15];
    const float* Wr1  = (const float*)d_in[16];
    const float* g1   = (const float*)d_in[17];
    const float* bt1  = (const float*)d_in[18];
    const float* m1   = (const float*)d_in[19];
    const float* v1   = (const float*)d_in[20];
    const float* W2   = (const float*)d_in[21];
    const float* al2  = (const float*)d_in[22];
    const float* ar2  = (const float*)d_in[23];
    const float* b2   = (const float*)d_in[24];
    const float* Wr2  = (const float*)d_in[25];
    const float* g2   = (const float*)d_in[26];
    const float* bt2  = (const float*)d_in[27];
    const float* v2m  = (const float*)d_in[28];   // m2
    const float* v2v  = (const float*)d_in[29];   // v2
    const float* We   = (const float*)d_in[30];
    const float* be   = (const float*)d_in[31];
    const float* Wc1  = (const float*)d_in[32];
    const float* bc1  = (const float*)d_in[33];
    const float* Wc2  = (const float*)d_in[34];
    const float* bc2  = (const float*)d_in[35];
    const float* Wc3  = (const float*)d_in[36];
    const float* bc3  = (const float*)d_in[37];
    float* out = (float*)d_out;

    const int N = in_sizes[0] / 128;
    const int E = in_sizes[2];

    char* p = (char*)d_ws;
    auto alloc = [&](size_t bytes) -> void* {
        void* r = (void*)p;
        p += (bytes + 255) & ~(size_t)255;
        return r;
    };
    int*   deg  = (int*)alloc((size_t)N * 4);
    int*   cur  = (int*)alloc((size_t)N * 4);
    int*   off  = (int*)alloc((size_t)(N + 1) * 4);
    int*   srcp = (int*)alloc((size_t)E * 4);
    int*   dstp = (int*)alloc((size_t)E * 4);
    float* ep   = (float*)alloc((size_t)E * 8 * 4);
    float* feat = (float*)alloc((size_t)N * 128 * 4);
    float* resf = (float*)alloc((size_t)N * 64 * 4);
    float* h1   = (float*)alloc((size_t)N * 128 * 4);
    float* h2   = (float*)alloc((size_t)N * 64 * 4);
    float* h3   = (float*)alloc((size_t)N * 32 * 4);
    float* el   = (float*)alloc((size_t)N * 8 * 4);
    float* er   = (float*)alloc((size_t)N * 8 * 4);
    float* u1   = h1;            // h1 dead by the time u1/u2 are built
    float* u2   = h1 + (size_t)N * 32;

    hipMemsetAsync(deg, 0, (size_t)N * 4, stream);
    hipMemsetAsync(cur, 0, (size_t)N * 4, stream);

    int eb = (E + 255) / 256;
    count_deg_k<<<eb, 256, 0, stream>>>(dst, deg, E);
    scan_k<<<1, 1024, 0, stream>>>(deg, off, N);
    scatter_k<<<eb, 256, 0, stream>>>(src, dst, off, cur, srcp, dstp, E);

    // ---- Layer 0: 128 -> 8x16, identity residual, ELU, BN ----
    gemm2_k<128,128><<<dim3((N + 63) / 64, 1), 256, 0, stream>>>(node_feats, W0, feat, W0, feat, N);
    elr_k<8,16><<<(N * 8 + 255) / 256, 256, 0, stream>>>(feat, al0, ar0, el, er, N);
    ep_k<8><<<eb, 256, 0, stream>>>(srcp, dstp, el, er, ep, E);
    gat_node_k<8,16,true><<<N, 64, 0, stream>>>(off, srcp, ep, feat, node_feats,
                                                b0, g0, bt0, m0, v0, h1);
    // ---- Layer 1: 128 -> 8x8, projected residual, ELU, BN (fused dual GEMM) ----
    gemm2_k<128,64><<<dim3((N + 127) / 128, 2), 256, 0, stream>>>(h1, W1, feat, Wr1, resf, N);
    elr_k<8,8><<<(N * 8 + 255) / 256, 256, 0, stream>>>(feat, al1, ar1, el, er, N);
    ep_k<8><<<eb, 256, 0, stream>>>(srcp, dstp, el, er, ep, E);
    gat_node_k<8,8,true><<<N, 64, 0, stream>>>(off, srcp, ep, feat, resf,
                                               b1, g1, bt1, m1, v1, h2);
    // ---- Layer 2: 64 -> 1x32, projected residual, no act, BN (fused dual GEMM) ----
    gemm2_k<64,32><<<dim3((N + 127) / 128, 2), 256, 0, stream>>>(h2, W2, feat, Wr2, resf, N);
    elr_k<1,32><<<(N + 255) / 256, 256, 0, stream>>>(feat, al2, ar2, el, er, N);
    ep_k<1><<<eb, 256, 0, stream>>>(srcp, dstp, el, er, ep, E);
    gat_node_k<1,32,false><<<N, 64, 0, stream>>>(off, srcp, ep, feat, resf,
                                                 b2, g2, bt2, v2m, v2v, h3);
    // ---- per-node halves of z1 (fused dual GEMM) ----
    gemm2_k<32,32><<<dim3((N + 127) / 128, 2), 256, 0, stream>>>(h3, Wc1, u1, Wc1 + 32 * 32, u2, N);
    // ---- fused edge classifier (MFMA) ----
    edge_cls_k<<<(E + 63) / 64, 256, 0, stream>>>(u1, u2, edge_feats, src, dst,
                                                  We, be, Wc1 + 64 * 32, bc1,
                                                  Wc2, bc2, Wc3, bc3, out, E);
}